// Round 2
// baseline (254.532 us; speedup 1.0000x reference)
//
#include <hip/hip_runtime.h>
#include <stdint.h>

typedef unsigned short u16;
typedef __attribute__((ext_vector_type(8))) short short8;
typedef __attribute__((ext_vector_type(4))) float f32x4;

#define NB    16
#define DIM   256
#define NTOK  1024

__device__ __forceinline__ u16 f2b(float f) {
    union { float f; uint32_t u; } v; v.f = f;
    uint32_t u = v.u;
    u += 0x7fffu + ((u >> 16) & 1u);
    return (u16)(u >> 16);
}
__device__ __forceinline__ uint32_t pack2(float a, float b) {
    return (uint32_t)f2b(a) | ((uint32_t)f2b(b) << 16);
}
__device__ __forceinline__ f32x4 mfma16(short8 a, short8 b, f32x4 c) {
    return __builtin_amdgcn_mfma_f32_16x16x32_bf16(a, b, c, 0, 0, 0);
}
__device__ __forceinline__ short8 ld8(const u16* p) {
    return *reinterpret_cast<const short8*>(p);
}

// ---------------- Kernel 1: pack x -> xbf (bf16 copy, [C][N]) + nodes (bf16 transpose, [N][C])
__global__ __launch_bounds__(256) void pack_kernel(const float* __restrict__ x,
                                                   u16* __restrict__ xbf,
                                                   u16* __restrict__ nodes) {
    __shared__ float tile[64][65];
    int tid = threadIdx.x;
    int blk = blockIdx.x;          // 1024 blocks
    int b  = blk >> 6;
    int t  = blk & 63;
    int c0 = (t >> 4) << 6;        // 0,64,128,192
    int n0 = (t & 15) << 6;        // 0..960
    const float* xb = x + (size_t)b * (DIM * NTOK);
    u16* xbb = xbf + (size_t)b * (DIM * NTOK);
#pragma unroll
    for (int i = 0; i < 16; i++) {
        int idx = i * 256 + tid;
        int cl = idx >> 6, nl = idx & 63;
        float f = xb[(c0 + cl) * NTOK + n0 + nl];
        tile[cl][nl] = f;
        xbb[(c0 + cl) * NTOK + n0 + nl] = f2b(f);
    }
    __syncthreads();
#pragma unroll
    for (int i = 0; i < 16; i++) {
        int idx = i * 256 + tid;
        int nl = idx >> 6, cl = idx & 63;
        nodes[(size_t)(b * NTOK + n0 + nl) * DIM + c0 + cl] = f2b(tile[cl][nl]);
    }
}

// ---------------- Kernel 2: convert 3 weight matrices to bf16 (proj_w, w1, w2)
__global__ __launch_bounds__(256) void wconv_kernel(const float* __restrict__ a,
                                                    const float* __restrict__ b,
                                                    const float* __restrict__ c,
                                                    u16* __restrict__ o) {
    int i = blockIdx.x * 256 + threadIdx.x;  // 0..196607
    const float* s = (i < 65536) ? a : (i < 131072) ? b : c;
    o[i] = f2b(s[i & 65535]);
}

// ---------------- Kernel 3: q = nodes @ proj_w^T + proj_b  (bf16 out, [N][C])
__global__ __launch_bounds__(256) void proj_kernel(const u16* __restrict__ nodes,
                                                   const u16* __restrict__ wbf,
                                                   const float* __restrict__ pb,
                                                   u16* __restrict__ qb) {
    int lane = threadIdx.x & 63;
    int w = threadIdx.x >> 6;
    int lo = lane & 15, hi = lane >> 4;
    int row0 = blockIdx.x * 64 + w * 16;
    const u16* arow = nodes + (size_t)(row0 + lo) * DIM + hi * 8;
    f32x4 acc[16];
#pragma unroll
    for (int i = 0; i < 16; i++) acc[i] = (f32x4){0.f, 0.f, 0.f, 0.f};
#pragma unroll
    for (int t = 0; t < 8; t++) {
        short8 a = ld8(arow + t * 32);
#pragma unroll
        for (int nf = 0; nf < 16; nf++) {
            short8 bfr = ld8(wbf + (nf * 16 + lo) * DIM + t * 32 + hi * 8);
            acc[nf] = mfma16(a, bfr, acc[nf]);
        }
    }
#pragma unroll
    for (int nf = 0; nf < 16; nf++) {
        int col = nf * 16 + lo;
        float bias = pb[col];
#pragma unroll
        for (int r = 0; r < 4; r++) {
            int row = row0 + hi * 4 + r;
            qb[(size_t)row * DIM + col] = f2b(acc[nf][r] + bias);
        }
    }
}

// ---------------- Kernel 4: flash attention, KV-split 4-way across the 4 waves of a block.
// Each wave: 16 q rows, kv range [w*256, w*256+256). In-block LDS combine at the end.
// Softmax tracked in exp2 domain: t = score * (0.0625*log2e); P = 2^(t - m).
__global__ __launch_bounds__(256, 4) void attn_kernel(const u16* __restrict__ qb,
                                                      const u16* __restrict__ xbf,
                                                      u16* __restrict__ agg) {
    __shared__ float part[4][16][128];   // 32 KB: [split][qrow][chan-half]
    __shared__ float2 mell[4][16];
    __shared__ float wsumLds[16];

    int lane = threadIdx.x & 63;
    int w = threadIdx.x >> 6;            // split index
    int lo = lane & 15, hi = lane >> 4;
    int b  = blockIdx.x & 15;            // batch-per-XCD-friendly mapping
    int qt = blockIdx.x >> 4;            // 0..63
    int q0 = qt * 16;
    const u16* qbb = qb  + (size_t)b * (NTOK * DIM);
    const u16* xbb = xbf + (size_t)b * (DIM * NTOK);

    short8 bq[8];
#pragma unroll
    for (int t = 0; t < 8; t++)
        bq[t] = ld8(qbb + (size_t)(q0 + lo) * DIM + t * 32 + hi * 8);

    f32x4 acc[16];
#pragma unroll
    for (int i = 0; i < 16; i++) acc[i] = (f32x4){0.f, 0.f, 0.f, 0.f};
    float m = -1e30f, ell = 0.f;
    const float C1 = 0.0625f * 1.44269504f;   // score scale folded with log2(e)
    const float THR = 11.5f;                  // defer-max threshold (exp2 domain, ~e^8)

    int kvbeg = w * 256;
    for (int kv0 = kvbeg; kv0 < kvbeg + 256; kv0 += 32) {
        f32x4 s0a = (f32x4){0.f,0.f,0.f,0.f}, s0b = (f32x4){0.f,0.f,0.f,0.f};
        f32x4 s1a = (f32x4){0.f,0.f,0.f,0.f}, s1b = (f32x4){0.f,0.f,0.f,0.f};
        const u16* k0p = qbb + (size_t)(kv0 + lo) * DIM + hi * 8;
        const u16* k1p = k0p + 16 * DIM;
#pragma unroll
        for (int t = 0; t < 8; t += 2) {
            s0a = mfma16(ld8(k0p + t * 32),       bq[t],     s0a);
            s0b = mfma16(ld8(k0p + (t + 1) * 32), bq[t + 1], s0b);
            s1a = mfma16(ld8(k1p + t * 32),       bq[t],     s1a);
            s1b = mfma16(ld8(k1p + (t + 1) * 32), bq[t + 1], s1b);
        }
        float p0[4], p1[4];
        float pm = -1e30f;
#pragma unroll
        for (int r = 0; r < 4; r++) {
            p0[r] = (s0a[r] + s0b[r]) * C1;
            p1[r] = (s1a[r] + s1b[r]) * C1;
            pm = fmaxf(pm, fmaxf(p0[r], p1[r]));
        }
        pm = fmaxf(pm, __shfl_xor(pm, 16));
        pm = fmaxf(pm, __shfl_xor(pm, 32));
        // defer-max: only rescale when some lane's tile max exceeds m + THR
        if (!__all(pm <= m + THR)) {
            float mnew = fmaxf(m, pm);
            float sc = exp2f(m - mnew);
            ell *= sc;
#pragma unroll
            for (int i = 0; i < 16; i++) {
                acc[i][0] *= sc; acc[i][1] *= sc; acc[i][2] *= sc; acc[i][3] *= sc;
            }
            m = mnew;
        }
        float psum = 0.f;
#pragma unroll
        for (int r = 0; r < 4; r++) {
            p0[r] = exp2f(p0[r] - m);
            p1[r] = exp2f(p1[r] - m);
            psum += p0[r] + p1[r];
        }
        psum += __shfl_xor(psum, 16);
        psum += __shfl_xor(psum, 32);
        ell += psum;

        // redistribute P (lane holds P[q=lo][kv=4*hi+r (+16)]) into B-fragment layout
        uint32_t pl0 = pack2(p0[0], p0[1]), ph0 = pack2(p0[2], p0[3]);
        uint32_t pl1 = pack2(p1[0], p1[1]), ph1 = pack2(p1[2], p1[3]);
        int srcA = ((hi & 1) << 5) | lo;
        int srcB = srcA + 16;
        uint32_t w0a = __shfl(pl0, srcA), w0b = __shfl(pl1, srcA);
        uint32_t w1a = __shfl(ph0, srcA), w1b = __shfl(ph1, srcA);
        uint32_t w2a = __shfl(pl0, srcB), w2b = __shfl(pl1, srcB);
        uint32_t w3a = __shfl(ph0, srcB), w3b = __shfl(ph1, srcB);
        bool sel = (hi >= 2);
        union { uint32_t u[4]; short8 v; } pu;
        pu.u[0] = sel ? w0b : w0a;
        pu.u[1] = sel ? w1b : w1a;
        pu.u[2] = sel ? w2b : w2a;
        pu.u[3] = sel ? w3b : w3a;
        short8 pfrag = pu.v;

        const u16* vp = xbb + kv0 + hi * 8;
#pragma unroll
        for (int mf = 0; mf < 16; mf++) {
            short8 a = ld8(vp + (size_t)(mf * 16 + lo) * NTOK);
            acc[mf] = mfma16(a, pfrag, acc[mf]);
        }
    }

    // ---- in-block combine of 4 KV-splits ----
    if (lane < 16) mell[w][lane] = make_float2(m, ell);
    __syncthreads();
    float M = -1e30f;
    float2 me[4];
#pragma unroll
    for (int s = 0; s < 4; s++) { me[s] = mell[s][lo]; M = fmaxf(M, me[s].x); }
    float wsum = 0.f;
#pragma unroll
    for (int s = 0; s < 4; s++) wsum += me[s].y * exp2f(me[s].x - M);
    float myscale = exp2f(m - M);
#pragma unroll
    for (int i = 0; i < 16; i++) {
        acc[i][0] *= myscale; acc[i][1] *= myscale; acc[i][2] *= myscale; acc[i][3] *= myscale;
    }
    if (threadIdx.x < 16) wsumLds[threadIdx.x] = wsum;  // wave 0, lo == tid

    char* partBase = (char*)&part[0][0][0];
#pragma unroll
    for (int h = 0; h < 2; h++) {
        __syncthreads();
        // write this wave's 8 channel-frags (swizzled against bank conflicts)
#pragma unroll
        for (int mf = 0; mf < 8; mf++) {
            int byte = w * 8192 + lo * 512 + (((mf * 64) + hi * 16) ^ ((lo & 7) << 4));
            *reinterpret_cast<f32x4*>(partBase + byte) = acc[h * 8 + mf];
        }
        __syncthreads();
        int q = threadIdx.x >> 4;
        int ci = (threadIdx.x & 15) * 8;
        f32x4 oa = (f32x4){0.f,0.f,0.f,0.f}, ob = (f32x4){0.f,0.f,0.f,0.f};
#pragma unroll
        for (int s = 0; s < 4; s++) {
            int base = s * 8192 + q * 512;
            int sw = (q & 7) << 4;
            f32x4 a = *reinterpret_cast<const f32x4*>(partBase + base + ((ci * 4) ^ sw));
            f32x4 c = *reinterpret_cast<const f32x4*>(partBase + base + ((ci * 4 + 16) ^ sw));
            oa[0]+=a[0]; oa[1]+=a[1]; oa[2]+=a[2]; oa[3]+=a[3];
            ob[0]+=c[0]; ob[1]+=c[1]; ob[2]+=c[2]; ob[3]+=c[3];
        }
        float rinv = 1.f / wsumLds[q];
        union { u16 s[8]; short8 v; } st;
#pragma unroll
        for (int j = 0; j < 4; j++) {
            st.s[j]     = f2b(oa[j] * rinv);
            st.s[j + 4] = f2b(ob[j] * rinv);
        }
        *reinterpret_cast<short8*>(agg + (size_t)(b * NTOK + q0 + q) * DIM + h * 128 + ci) = st.v;
    }
}

// ---------------- Kernel 5: FFN + residual.
// h = gelu(agg @ w1^T + b1); out^T = w2 @ h^T + b2; y = x + out^T (x layout)
__global__ __launch_bounds__(256) void ffn_kernel(const u16* __restrict__ agg,
                                                  const u16* __restrict__ wbf,
                                                  const float* __restrict__ b1,
                                                  const float* __restrict__ b2,
                                                  const float* __restrict__ x,
                                                  float* __restrict__ out) {
    __shared__ u16 hl[64][264];
    int lane = threadIdx.x & 63;
    int w = threadIdx.x >> 6;
    int lo = lane & 15, hi = lane >> 4;
    int row0 = blockIdx.x * 64;     // 256 blocks
    int rw = row0 + w * 16;
    const u16* w1b = wbf + 65536;
    const u16* w2b = wbf + 131072;

    f32x4 acc[16];
#pragma unroll
    for (int i = 0; i < 16; i++) acc[i] = (f32x4){0.f, 0.f, 0.f, 0.f};
    const u16* arow = agg + (size_t)(rw + lo) * DIM + hi * 8;
#pragma unroll
    for (int t = 0; t < 8; t++) {
        short8 a = ld8(arow + t * 32);
#pragma unroll
        for (int nf = 0; nf < 16; nf++) {
            short8 bfr = ld8(w1b + (nf * 16 + lo) * DIM + t * 32 + hi * 8);
            acc[nf] = mfma16(a, bfr, acc[nf]);
        }
    }
#pragma unroll
    for (int nf = 0; nf < 16; nf++) {
        int f = nf * 16 + lo;
        float bias = b1[f];
#pragma unroll
        for (int r = 0; r < 4; r++) {
            float v = acc[nf][r] + bias;
            float g = 0.5f * v * (1.f + erff(v * 0.70710678f));
            hl[w * 16 + hi * 4 + r][f] = f2b(g);
        }
    }
    __syncthreads();

    f32x4 acc2[16];
#pragma unroll
    for (int i = 0; i < 16; i++) acc2[i] = (f32x4){0.f, 0.f, 0.f, 0.f};
#pragma unroll
    for (int t = 0; t < 8; t++) {
        short8 bh = ld8(&hl[w * 16 + lo][t * 32 + hi * 8]);
#pragma unroll
        for (int mf = 0; mf < 16; mf++) {
            short8 a = ld8(w2b + (mf * 16 + lo) * DIM + t * 32 + hi * 8);
            acc2[mf] = mfma16(a, bh, acc2[mf]);
        }
    }
    int bidx = row0 >> 10;
    int n = (rw & 1023) + lo;
#pragma unroll
    for (int mf = 0; mf < 16; mf++) {
#pragma unroll
        for (int r = 0; r < 4; r++) {
            int co = mf * 16 + hi * 4 + r;
            size_t addr = (size_t)bidx * (DIM * NTOK) + (size_t)co * NTOK + n;
            out[addr] = acc2[mf][r] + b2[co] + x[addr];
        }
    }
}

extern "C" void kernel_launch(void* const* d_in, const int* in_sizes, int n_in,
                              void* d_out, int out_size, void* d_ws, size_t ws_size,
                              hipStream_t stream) {
    const float* x      = (const float*)d_in[0];
    const float* proj_w = (const float*)d_in[1];
    const float* proj_b = (const float*)d_in[2];
    const float* w1     = (const float*)d_in[3];
    const float* b1     = (const float*)d_in[4];
    const float* w2     = (const float*)d_in[5];
    const float* b2     = (const float*)d_in[6];
    float* out = (float*)d_out;

    u16* xbf   = (u16*)d_ws;                 // 16*256*1024 = 4,194,304 elems
    u16* nodes = xbf   + 4194304;
    u16* qb    = nodes + 4194304;
    u16* agg   = qb    + 4194304;
    u16* wbf   = agg   + 4194304;            // 3*65536 elems

    pack_kernel <<<1024, 256, 0, stream>>>(x, xbf, nodes);
    wconv_kernel<<<768,  256, 0, stream>>>(proj_w, w1, w2, wbf);
    proj_kernel <<<256,  256, 0, stream>>>(nodes, wbf, proj_b, qb);
    attn_kernel <<<1024, 256, 0, stream>>>(qb, xbf, agg);
    ffn_kernel  <<<256,  256, 0, stream>>>(agg, wbf, b1, b2, x, out);
}

// Round 3
// 202.580 us; speedup vs baseline: 1.2564x; 1.2564x over previous
//
#include <hip/hip_runtime.h>
#include <stdint.h>

typedef unsigned short u16;
typedef __attribute__((ext_vector_type(8))) short short8;
typedef __attribute__((ext_vector_type(4))) float f32x4;

#define NB    16
#define DIM   256
#define NTOK  1024

__device__ __forceinline__ u16 f2b(float f) {
    union { float f; uint32_t u; } v; v.f = f;
    uint32_t u = v.u;
    u += 0x7fffu + ((u >> 16) & 1u);
    return (u16)(u >> 16);
}
__device__ __forceinline__ uint32_t pack2(float a, float b) {
    return (uint32_t)f2b(a) | ((uint32_t)f2b(b) << 16);
}
__device__ __forceinline__ f32x4 mfma16(short8 a, short8 b, f32x4 c) {
    return __builtin_amdgcn_mfma_f32_16x16x32_bf16(a, b, c, 0, 0, 0);
}
__device__ __forceinline__ short8 ld8(const u16* p) {
    return *reinterpret_cast<const short8*>(p);
}

// ---------------- Kernel 1: pack x -> xbf (bf16 copy, [C][N]) + nodes (bf16 transpose, [N][C])
__global__ __launch_bounds__(256) void pack_kernel(const float* __restrict__ x,
                                                   u16* __restrict__ xbf,
                                                   u16* __restrict__ nodes) {
    __shared__ float tile[64][65];
    int tid = threadIdx.x;
    int blk = blockIdx.x;          // 1024 blocks
    int b  = blk >> 6;
    int t  = blk & 63;
    int c0 = (t >> 4) << 6;        // 0,64,128,192
    int n0 = (t & 15) << 6;        // 0..960
    const float* xb = x + (size_t)b * (DIM * NTOK);
    u16* xbb = xbf + (size_t)b * (DIM * NTOK);
#pragma unroll
    for (int i = 0; i < 16; i++) {
        int idx = i * 256 + tid;
        int cl = idx >> 6, nl = idx & 63;
        float f = xb[(c0 + cl) * NTOK + n0 + nl];
        tile[cl][nl] = f;
        xbb[(c0 + cl) * NTOK + n0 + nl] = f2b(f);
    }
    __syncthreads();
#pragma unroll
    for (int i = 0; i < 16; i++) {
        int idx = i * 256 + tid;
        int nl = idx >> 6, cl = idx & 63;
        nodes[(size_t)(b * NTOK + n0 + nl) * DIM + c0 + cl] = f2b(tile[cl][nl]);
    }
}

// ---------------- Kernel 2: convert 3 weight matrices to bf16 (proj_w, w1, w2)
__global__ __launch_bounds__(256) void wconv_kernel(const float* __restrict__ a,
                                                    const float* __restrict__ b,
                                                    const float* __restrict__ c,
                                                    u16* __restrict__ o) {
    int i = blockIdx.x * 256 + threadIdx.x;  // 0..196607
    const float* s = (i < 65536) ? a : (i < 131072) ? b : c;
    o[i] = f2b(s[i & 65535]);
}

// ---------------- Kernel 3: q = nodes @ proj_w^T + proj_b  (bf16 out, [N][C])
// column-split 2-way: 512 blocks, each wave 16 rows x 128 cols.
__global__ __launch_bounds__(256) void proj_kernel(const u16* __restrict__ nodes,
                                                   const u16* __restrict__ wbf,
                                                   const float* __restrict__ pb,
                                                   u16* __restrict__ qb) {
    int lane = threadIdx.x & 63;
    int w = threadIdx.x >> 6;
    int lo = lane & 15, hi = lane >> 4;
    int ch = blockIdx.x & 1;               // column half
    int row0 = (blockIdx.x >> 1) * 64 + w * 16;
    const u16* arow = nodes + (size_t)(row0 + lo) * DIM + hi * 8;
    f32x4 acc[8];
#pragma unroll
    for (int i = 0; i < 8; i++) acc[i] = (f32x4){0.f, 0.f, 0.f, 0.f};
#pragma unroll
    for (int t = 0; t < 8; t++) {
        short8 a = ld8(arow + t * 32);
#pragma unroll
        for (int nf = 0; nf < 8; nf++) {
            short8 bfr = ld8(wbf + ((ch * 8 + nf) * 16 + lo) * DIM + t * 32 + hi * 8);
            acc[nf] = mfma16(a, bfr, acc[nf]);
        }
    }
#pragma unroll
    for (int nf = 0; nf < 8; nf++) {
        int col = (ch * 8 + nf) * 16 + lo;
        float bias = pb[col];
#pragma unroll
        for (int r = 0; r < 4; r++) {
            int row = row0 + hi * 4 + r;
            qb[(size_t)row * DIM + col] = f2b(acc[nf][r] + bias);
        }
    }
}

// ---------------- Kernel 4: flash attention, KV-split 2-way across wave pairs.
// Block = 4 waves = 2 q-tiles x 2 kv-halves. Wave (qsel,kvh): 16 q rows, kv in
// [kvh*512, kvh*512+512). In-block LDS combine: each wave keeps channel-half
// kvh and gives the other half to its partner (w^1).
__global__ __launch_bounds__(256) void attn_kernel(const u16* __restrict__ qb,
                                                   const u16* __restrict__ xbf,
                                                   u16* __restrict__ agg) {
    __shared__ float part[4][16][128];   // 32 KB giveaway halves
    __shared__ float2 mell[4][16];

    int lane = threadIdx.x & 63;
    int w = threadIdx.x >> 6;            // 0..3
    int qsel = w >> 1, kvh = w & 1;
    int lo = lane & 15, hi = lane >> 4;
    int b  = blockIdx.x & 15;            // batch-per-XCD-friendly mapping
    int qpair = blockIdx.x >> 4;         // 0..31
    int q0 = (qpair * 2 + qsel) * 16;
    const u16* qbb = qb  + (size_t)b * (NTOK * DIM);
    const u16* xbb = xbf + (size_t)b * (DIM * NTOK);

    short8 bq[8];
#pragma unroll
    for (int t = 0; t < 8; t++)
        bq[t] = ld8(qbb + (size_t)(q0 + lo) * DIM + t * 32 + hi * 8);

    f32x4 acc[16];
#pragma unroll
    for (int i = 0; i < 16; i++) acc[i] = (f32x4){0.f, 0.f, 0.f, 0.f};
    float m = -1e30f, ell = 0.f;
    const float C1 = 0.0625f * 1.44269504f;   // score scale folded with log2(e)
    const float THR = 11.5f;                  // defer-max threshold (exp2 domain)

    int kvbeg = kvh * 512;
    for (int kv0 = kvbeg; kv0 < kvbeg + 512; kv0 += 32) {
        f32x4 s0a = (f32x4){0.f,0.f,0.f,0.f}, s0b = (f32x4){0.f,0.f,0.f,0.f};
        f32x4 s1a = (f32x4){0.f,0.f,0.f,0.f}, s1b = (f32x4){0.f,0.f,0.f,0.f};
        const u16* k0p = qbb + (size_t)(kv0 + lo) * DIM + hi * 8;
        const u16* k1p = k0p + 16 * DIM;
#pragma unroll
        for (int t = 0; t < 8; t += 2) {
            s0a = mfma16(ld8(k0p + t * 32),       bq[t],     s0a);
            s0b = mfma16(ld8(k0p + (t + 1) * 32), bq[t + 1], s0b);
            s1a = mfma16(ld8(k1p + t * 32),       bq[t],     s1a);
            s1b = mfma16(ld8(k1p + (t + 1) * 32), bq[t + 1], s1b);
        }
        float p0[4], p1[4];
        float pm = -1e30f;
#pragma unroll
        for (int r = 0; r < 4; r++) {
            p0[r] = (s0a[r] + s0b[r]) * C1;
            p1[r] = (s1a[r] + s1b[r]) * C1;
            pm = fmaxf(pm, fmaxf(p0[r], p1[r]));
        }
        pm = fmaxf(pm, __shfl_xor(pm, 16));
        pm = fmaxf(pm, __shfl_xor(pm, 32));
        if (!__all(pm <= m + THR)) {
            float mnew = fmaxf(m, pm);
            float sc = exp2f(m - mnew);
            ell *= sc;
#pragma unroll
            for (int i = 0; i < 16; i++) {
                acc[i][0] *= sc; acc[i][1] *= sc; acc[i][2] *= sc; acc[i][3] *= sc;
            }
            m = mnew;
        }
        float psum = 0.f;
#pragma unroll
        for (int r = 0; r < 4; r++) {
            p0[r] = exp2f(p0[r] - m);
            p1[r] = exp2f(p1[r] - m);
            psum += p0[r] + p1[r];
        }
        psum += __shfl_xor(psum, 16);
        psum += __shfl_xor(psum, 32);
        ell += psum;

        // redistribute P (lane holds P[q=lo][kv=4*hi+r (+16)]) into B-fragment layout
        uint32_t pl0 = pack2(p0[0], p0[1]), ph0 = pack2(p0[2], p0[3]);
        uint32_t pl1 = pack2(p1[0], p1[1]), ph1 = pack2(p1[2], p1[3]);
        int srcA = ((hi & 1) << 5) | lo;
        int srcB = srcA + 16;
        uint32_t w0a = __shfl(pl0, srcA), w0b = __shfl(pl1, srcA);
        uint32_t w1a = __shfl(ph0, srcA), w1b = __shfl(ph1, srcA);
        uint32_t w2a = __shfl(pl0, srcB), w2b = __shfl(pl1, srcB);
        uint32_t w3a = __shfl(ph0, srcB), w3b = __shfl(ph1, srcB);
        bool sel = (hi >= 2);
        union { uint32_t u[4]; short8 v; } pu;
        pu.u[0] = sel ? w0b : w0a;
        pu.u[1] = sel ? w1b : w1a;
        pu.u[2] = sel ? w2b : w2a;
        pu.u[3] = sel ? w3b : w3a;
        short8 pfrag = pu.v;

        const u16* vp = xbb + kv0 + hi * 8;
#pragma unroll
        for (int mf = 0; mf < 16; mf++) {
            short8 a = ld8(vp + (size_t)(mf * 16 + lo) * NTOK);
            acc[mf] = mfma16(a, pfrag, acc[mf]);
        }
    }

    // ---- in-block combine across the 2 KV-halves (partner = w^1) ----
    if (lane < 16) mell[w][lane] = make_float2(m, ell);
    __syncthreads();
    float2 op = mell[w ^ 1][lo];
    float M = fmaxf(m, op.x);
    float wsum = ell * exp2f(m - M) + op.y * exp2f(op.x - M);
    float s = exp2f(m - M);
#pragma unroll
    for (int i = 0; i < 16; i++) {
        acc[i][0] *= s; acc[i][1] *= s; acc[i][2] *= s; acc[i][3] *= s;
    }
    // giveaway half: kvh==0 gives frags 8..15, kvh==1 gives frags 0..7
    int gbase = (kvh ^ 1) * 8;
    int kbase = kvh * 8;
    char* pbase = (char*)part;
#pragma unroll
    for (int mf = 0; mf < 8; mf++) {
        int byte = w * 8192 + lo * 512 + ((mf * 64 + hi * 16) ^ ((lo & 7) << 4));
        *reinterpret_cast<f32x4*>(pbase + byte) = acc[gbase + mf];
    }
    __syncthreads();
    float rinv = 1.f / wsum;
#pragma unroll
    for (int mf = 0; mf < 8; mf++) {
        int byte = (w ^ 1) * 8192 + lo * 512 + ((mf * 64 + hi * 16) ^ ((lo & 7) << 4));
        f32x4 o = *reinterpret_cast<const f32x4*>(pbase + byte);
        f32x4 a = acc[kbase + mf];
        ushort4 st;
        st.x = f2b((a[0] + o[0]) * rinv);
        st.y = f2b((a[1] + o[1]) * rinv);
        st.z = f2b((a[2] + o[2]) * rinv);
        st.w = f2b((a[3] + o[3]) * rinv);
        *reinterpret_cast<ushort4*>(agg + (size_t)(b * NTOK + q0 + lo) * DIM +
                                    (kbase + mf) * 16 + hi * 4) = st;
    }
}

// ---------------- Kernel 5: FFN + residual, 8-wave blocks (4 rowtiles x 2 colhalves).
// h = gelu(agg @ w1^T + b1); out^T = w2 @ h^T + b2; y = x + out^T (x layout)
__global__ __launch_bounds__(512) void ffn_kernel(const u16* __restrict__ agg,
                                                  const u16* __restrict__ wbf,
                                                  const float* __restrict__ b1,
                                                  const float* __restrict__ b2,
                                                  const float* __restrict__ x,
                                                  float* __restrict__ out) {
    __shared__ u16 hl[64][264];
    int lane = threadIdx.x & 63;
    int w = threadIdx.x >> 6;        // 0..7
    int wr = w & 3, wc = w >> 2;
    int lo = lane & 15, hi = lane >> 4;
    int row0 = blockIdx.x * 64;      // 256 blocks
    int rw = row0 + wr * 16;
    const u16* w1b = wbf + 65536;
    const u16* w2b = wbf + 131072;

    f32x4 acc[8];
#pragma unroll
    for (int i = 0; i < 8; i++) acc[i] = (f32x4){0.f, 0.f, 0.f, 0.f};
    const u16* arow = agg + (size_t)(rw + lo) * DIM + hi * 8;
#pragma unroll
    for (int t = 0; t < 8; t++) {
        short8 a = ld8(arow + t * 32);
#pragma unroll
        for (int nf = 0; nf < 8; nf++) {
            short8 bfr = ld8(w1b + ((wc * 8 + nf) * 16 + lo) * DIM + t * 32 + hi * 8);
            acc[nf] = mfma16(a, bfr, acc[nf]);
        }
    }
#pragma unroll
    for (int nf = 0; nf < 8; nf++) {
        int f = (wc * 8 + nf) * 16 + lo;
        float bias = b1[f];
#pragma unroll
        for (int r = 0; r < 4; r++) {
            float v = acc[nf][r] + bias;
            float g = 0.5f * v * (1.f + erff(v * 0.70710678f));
            hl[wr * 16 + hi * 4 + r][f] = f2b(g);
        }
    }
    __syncthreads();

    f32x4 acc2[8];
#pragma unroll
    for (int i = 0; i < 8; i++) acc2[i] = (f32x4){0.f, 0.f, 0.f, 0.f};
#pragma unroll
    for (int t = 0; t < 8; t++) {
        short8 bh = ld8(&hl[wr * 16 + lo][t * 32 + hi * 8]);
#pragma unroll
        for (int mf = 0; mf < 8; mf++) {
            short8 a = ld8(w2b + ((wc * 8 + mf) * 16 + lo) * DIM + t * 32 + hi * 8);
            acc2[mf] = mfma16(a, bh, acc2[mf]);
        }
    }
    int bidx = row0 >> 10;
    int n = (rw & 1023) + lo;
#pragma unroll
    for (int mf = 0; mf < 8; mf++) {
#pragma unroll
        for (int r = 0; r < 4; r++) {
            int co = (wc * 8 + mf) * 16 + hi * 4 + r;
            size_t addr = (size_t)bidx * (DIM * NTOK) + (size_t)co * NTOK + n;
            out[addr] = acc2[mf][r] + b2[co] + x[addr];
        }
    }
}

extern "C" void kernel_launch(void* const* d_in, const int* in_sizes, int n_in,
                              void* d_out, int out_size, void* d_ws, size_t ws_size,
                              hipStream_t stream) {
    const float* x      = (const float*)d_in[0];
    const float* proj_w = (const float*)d_in[1];
    const float* proj_b = (const float*)d_in[2];
    const float* w1     = (const float*)d_in[3];
    const float* b1     = (const float*)d_in[4];
    const float* w2     = (const float*)d_in[5];
    const float* b2     = (const float*)d_in[6];
    float* out = (float*)d_out;

    u16* xbf   = (u16*)d_ws;                 // 16*256*1024 = 4,194,304 elems
    u16* nodes = xbf   + 4194304;
    u16* qb    = nodes + 4194304;
    u16* agg   = qb    + 4194304;
    u16* wbf   = agg   + 4194304;            // 3*65536 elems

    pack_kernel <<<1024, 256, 0, stream>>>(x, xbf, nodes);
    wconv_kernel<<<768,  256, 0, stream>>>(proj_w, w1, w2, wbf);
    proj_kernel <<<512,  256, 0, stream>>>(nodes, wbf, proj_b, qb);
    attn_kernel <<<512,  256, 0, stream>>>(qb, xbf, agg);
    ffn_kernel  <<<256,  512, 0, stream>>>(agg, wbf, b1, b2, x, out);
}

// Round 4
// 191.848 us; speedup vs baseline: 1.3267x; 1.0559x over previous
//
#include <hip/hip_runtime.h>
#include <stdint.h>

typedef unsigned short u16;
typedef __attribute__((ext_vector_type(8))) short short8;
typedef __attribute__((ext_vector_type(4))) float f32x4;

#define NB    16
#define DIM   256
#define NTOK  1024

__device__ __forceinline__ u16 f2b(float f) {
    union { float f; uint32_t u; } v; v.f = f;
    uint32_t u = v.u;
    u += 0x7fffu + ((u >> 16) & 1u);
    return (u16)(u >> 16);
}
__device__ __forceinline__ uint32_t pack2(float a, float b) {
    return (uint32_t)f2b(a) | ((uint32_t)f2b(b) << 16);
}
__device__ __forceinline__ f32x4 mfma16(short8 a, short8 b, f32x4 c) {
    return __builtin_amdgcn_mfma_f32_16x16x32_bf16(a, b, c, 0, 0, 0);
}
__device__ __forceinline__ short8 ld8(const u16* p) {
    return *reinterpret_cast<const short8*>(p);
}

// ---------------- Kernel 1: pack x -> xbf (bf16 copy, [C][N]) + nodes (bf16 transpose, [N][C])
__global__ __launch_bounds__(256) void pack_kernel(const float* __restrict__ x,
                                                   u16* __restrict__ xbf,
                                                   u16* __restrict__ nodes) {
    __shared__ float tile[64][65];
    int tid = threadIdx.x;
    int blk = blockIdx.x;          // 1024 blocks
    int b  = blk >> 6;
    int t  = blk & 63;
    int c0 = (t >> 4) << 6;        // 0,64,128,192
    int n0 = (t & 15) << 6;        // 0..960
    const float* xb = x + (size_t)b * (DIM * NTOK);
    u16* xbb = xbf + (size_t)b * (DIM * NTOK);
#pragma unroll
    for (int i = 0; i < 16; i++) {
        int idx = i * 256 + tid;
        int cl = idx >> 6, nl = idx & 63;
        float f = xb[(c0 + cl) * NTOK + n0 + nl];
        tile[cl][nl] = f;
        xbb[(c0 + cl) * NTOK + n0 + nl] = f2b(f);
    }
    __syncthreads();
#pragma unroll
    for (int i = 0; i < 16; i++) {
        int idx = i * 256 + tid;
        int nl = idx >> 6, cl = idx & 63;
        nodes[(size_t)(b * NTOK + n0 + nl) * DIM + c0 + cl] = f2b(tile[cl][nl]);
    }
}

// ---------------- Kernel 2: convert 3 weight matrices to bf16 (proj_w, w1, w2)
__global__ __launch_bounds__(256) void wconv_kernel(const float* __restrict__ a,
                                                    const float* __restrict__ b,
                                                    const float* __restrict__ c,
                                                    u16* __restrict__ o) {
    int i = blockIdx.x * 256 + threadIdx.x;  // 0..196607
    const float* s = (i < 65536) ? a : (i < 131072) ? b : c;
    o[i] = f2b(s[i & 65535]);
}

// ---------------- Kernel 3: q = nodes @ proj_w^T + proj_b  (bf16 out, [N][C])
// column-split 2-way: 512 blocks, each wave 16 rows x 128 cols.
__global__ __launch_bounds__(256) void proj_kernel(const u16* __restrict__ nodes,
                                                   const u16* __restrict__ wbf,
                                                   const float* __restrict__ pb,
                                                   u16* __restrict__ qb) {
    int lane = threadIdx.x & 63;
    int w = threadIdx.x >> 6;
    int lo = lane & 15, hi = lane >> 4;
    int ch = blockIdx.x & 1;               // column half
    int row0 = (blockIdx.x >> 1) * 64 + w * 16;
    const u16* arow = nodes + (size_t)(row0 + lo) * DIM + hi * 8;
    f32x4 acc[8];
#pragma unroll
    for (int i = 0; i < 8; i++) acc[i] = (f32x4){0.f, 0.f, 0.f, 0.f};
#pragma unroll
    for (int t = 0; t < 8; t++) {
        short8 a = ld8(arow + t * 32);
#pragma unroll
        for (int nf = 0; nf < 8; nf++) {
            short8 bfr = ld8(wbf + ((ch * 8 + nf) * 16 + lo) * DIM + t * 32 + hi * 8);
            acc[nf] = mfma16(a, bfr, acc[nf]);
        }
    }
#pragma unroll
    for (int nf = 0; nf < 8; nf++) {
        int col = (ch * 8 + nf) * 16 + lo;
        float bias = pb[col];
#pragma unroll
        for (int r = 0; r < 4; r++) {
            int row = row0 + hi * 4 + r;
            qb[(size_t)row * DIM + col] = f2b(acc[nf][r] + bias);
        }
    }
}

// ---------------- Kernel 4: flash attention, KV-split 4-way across the 4 waves of a block.
// Each wave: 16 q rows, kv range [w*256, w*256+256). In-block LDS combine at the end.
// ALL accumulator indices are compile-time constants (rule #20).
__global__ __launch_bounds__(256) void attn_kernel(const u16* __restrict__ qb,
                                                   const u16* __restrict__ xbf,
                                                   u16* __restrict__ agg) {
    __shared__ float part[4][16][128];   // 32 KB: [split][qrow][chan-half]
    __shared__ float2 mell[4][16];
    __shared__ float wsumLds[16];

    int lane = threadIdx.x & 63;
    int w = threadIdx.x >> 6;            // split index
    int lo = lane & 15, hi = lane >> 4;
    int b  = blockIdx.x & 15;            // batch-per-XCD-friendly mapping
    int qt = blockIdx.x >> 4;            // 0..63
    int q0 = qt * 16;
    const u16* qbb = qb  + (size_t)b * (NTOK * DIM);
    const u16* xbb = xbf + (size_t)b * (DIM * NTOK);

    short8 bq[8];
#pragma unroll
    for (int t = 0; t < 8; t++)
        bq[t] = ld8(qbb + (size_t)(q0 + lo) * DIM + t * 32 + hi * 8);

    f32x4 acc[16];
#pragma unroll
    for (int i = 0; i < 16; i++) acc[i] = (f32x4){0.f, 0.f, 0.f, 0.f};
    float m = -1e30f, ell = 0.f;
    const float C1 = 0.0625f * 1.44269504f;   // score scale folded with log2(e)
    const float THR = 11.5f;                  // defer-max threshold (exp2 domain)

    int kvbeg = w * 256;
    for (int kv0 = kvbeg; kv0 < kvbeg + 256; kv0 += 32) {
        f32x4 s0a = (f32x4){0.f,0.f,0.f,0.f}, s0b = (f32x4){0.f,0.f,0.f,0.f};
        f32x4 s1a = (f32x4){0.f,0.f,0.f,0.f}, s1b = (f32x4){0.f,0.f,0.f,0.f};
        const u16* k0p = qbb + (size_t)(kv0 + lo) * DIM + hi * 8;
        const u16* k1p = k0p + 16 * DIM;
#pragma unroll
        for (int t = 0; t < 8; t += 2) {
            s0a = mfma16(ld8(k0p + t * 32),       bq[t],     s0a);
            s0b = mfma16(ld8(k0p + (t + 1) * 32), bq[t + 1], s0b);
            s1a = mfma16(ld8(k1p + t * 32),       bq[t],     s1a);
            s1b = mfma16(ld8(k1p + (t + 1) * 32), bq[t + 1], s1b);
        }
        float p0[4], p1[4];
        float pm = -1e30f;
#pragma unroll
        for (int r = 0; r < 4; r++) {
            p0[r] = (s0a[r] + s0b[r]) * C1;
            p1[r] = (s1a[r] + s1b[r]) * C1;
            pm = fmaxf(pm, fmaxf(p0[r], p1[r]));
        }
        pm = fmaxf(pm, __shfl_xor(pm, 16));
        pm = fmaxf(pm, __shfl_xor(pm, 32));
        if (!__all(pm <= m + THR)) {
            float mnew = fmaxf(m, pm);
            float sc = exp2f(m - mnew);
            ell *= sc;
#pragma unroll
            for (int i = 0; i < 16; i++) {
                acc[i][0] *= sc; acc[i][1] *= sc; acc[i][2] *= sc; acc[i][3] *= sc;
            }
            m = mnew;
        }
        float psum = 0.f;
#pragma unroll
        for (int r = 0; r < 4; r++) {
            p0[r] = exp2f(p0[r] - m);
            p1[r] = exp2f(p1[r] - m);
            psum += p0[r] + p1[r];
        }
        psum += __shfl_xor(psum, 16);
        psum += __shfl_xor(psum, 32);
        ell += psum;

        // redistribute P (lane holds P[q=lo][kv=4*hi+r (+16)]) into B-fragment layout
        uint32_t pl0 = pack2(p0[0], p0[1]), ph0 = pack2(p0[2], p0[3]);
        uint32_t pl1 = pack2(p1[0], p1[1]), ph1 = pack2(p1[2], p1[3]);
        int srcA = ((hi & 1) << 5) | lo;
        int srcB = srcA + 16;
        uint32_t w0a = __shfl(pl0, srcA), w0b = __shfl(pl1, srcA);
        uint32_t w1a = __shfl(ph0, srcA), w1b = __shfl(ph1, srcA);
        uint32_t w2a = __shfl(pl0, srcB), w2b = __shfl(pl1, srcB);
        uint32_t w3a = __shfl(ph0, srcB), w3b = __shfl(ph1, srcB);
        bool sel = (hi >= 2);
        union { uint32_t u[4]; short8 v; } pu;
        pu.u[0] = sel ? w0b : w0a;
        pu.u[1] = sel ? w1b : w1a;
        pu.u[2] = sel ? w2b : w2a;
        pu.u[3] = sel ? w3b : w3a;
        short8 pfrag = pu.v;

        const u16* vp = xbb + kv0 + hi * 8;
#pragma unroll
        for (int mf = 0; mf < 16; mf++) {
            short8 a = ld8(vp + (size_t)(mf * 16 + lo) * NTOK);
            acc[mf] = mfma16(a, pfrag, acc[mf]);
        }
    }

    // ---- in-block combine of 4 KV-splits (all acc indices static) ----
    if (lane < 16) mell[w][lane] = make_float2(m, ell);
    __syncthreads();
    float M = -1e30f;
    float2 me[4];
#pragma unroll
    for (int s = 0; s < 4; s++) { me[s] = mell[s][lo]; M = fmaxf(M, me[s].x); }
    float wsum = 0.f;
#pragma unroll
    for (int s = 0; s < 4; s++) wsum += me[s].y * exp2f(me[s].x - M);
    float myscale = exp2f(m - M);
#pragma unroll
    for (int i = 0; i < 16; i++) {
        acc[i][0] *= myscale; acc[i][1] *= myscale; acc[i][2] *= myscale; acc[i][3] *= myscale;
    }
    if (threadIdx.x < 16) wsumLds[threadIdx.x] = wsum;  // wave 0, lo == tid

    char* partBase = (char*)&part[0][0][0];
#pragma unroll
    for (int h = 0; h < 2; h++) {
        __syncthreads();
#pragma unroll
        for (int mf = 0; mf < 8; mf++) {
            int byte = w * 8192 + lo * 512 + (((mf * 64) + hi * 16) ^ ((lo & 7) << 4));
            *reinterpret_cast<f32x4*>(partBase + byte) = acc[h * 8 + mf];
        }
        __syncthreads();
        int q = threadIdx.x >> 4;
        int ci = (threadIdx.x & 15) * 8;
        f32x4 oa = (f32x4){0.f,0.f,0.f,0.f}, ob = (f32x4){0.f,0.f,0.f,0.f};
#pragma unroll
        for (int s = 0; s < 4; s++) {
            int base = s * 8192 + q * 512;
            int sw = (q & 7) << 4;
            f32x4 a = *reinterpret_cast<const f32x4*>(partBase + base + ((ci * 4) ^ sw));
            f32x4 c = *reinterpret_cast<const f32x4*>(partBase + base + ((ci * 4 + 16) ^ sw));
            oa[0]+=a[0]; oa[1]+=a[1]; oa[2]+=a[2]; oa[3]+=a[3];
            ob[0]+=c[0]; ob[1]+=c[1]; ob[2]+=c[2]; ob[3]+=c[3];
        }
        float rinv = 1.f / wsumLds[q];
        union { u16 s[8]; short8 v; } st;
#pragma unroll
        for (int j = 0; j < 4; j++) {
            st.s[j]     = f2b(oa[j] * rinv);
            st.s[j + 4] = f2b(ob[j] * rinv);
        }
        *reinterpret_cast<short8*>(agg + (size_t)(b * NTOK + q0 + q) * DIM + h * 128 + ci) = st.v;
    }
}

// ---------------- Kernel 5: FFN + residual, 8-wave blocks (4 rowtiles x 2 colhalves).
// h = gelu(agg @ w1^T + b1); out^T = w2 @ h^T + b2; y = x + out^T (x layout)
__global__ __launch_bounds__(512) void ffn_kernel(const u16* __restrict__ agg,
                                                  const u16* __restrict__ wbf,
                                                  const float* __restrict__ b1,
                                                  const float* __restrict__ b2,
                                                  const float* __restrict__ x,
                                                  float* __restrict__ out) {
    __shared__ u16 hl[64][264];
    int lane = threadIdx.x & 63;
    int w = threadIdx.x >> 6;        // 0..7
    int wr = w & 3, wc = w >> 2;
    int lo = lane & 15, hi = lane >> 4;
    int row0 = blockIdx.x * 64;      // 256 blocks
    int rw = row0 + wr * 16;
    const u16* w1b = wbf + 65536;
    const u16* w2b = wbf + 131072;

    f32x4 acc[8];
#pragma unroll
    for (int i = 0; i < 8; i++) acc[i] = (f32x4){0.f, 0.f, 0.f, 0.f};
    const u16* arow = agg + (size_t)(rw + lo) * DIM + hi * 8;
#pragma unroll
    for (int t = 0; t < 8; t++) {
        short8 a = ld8(arow + t * 32);
#pragma unroll
        for (int nf = 0; nf < 8; nf++) {
            short8 bfr = ld8(w1b + ((wc * 8 + nf) * 16 + lo) * DIM + t * 32 + hi * 8);
            acc[nf] = mfma16(a, bfr, acc[nf]);
        }
    }
#pragma unroll
    for (int nf = 0; nf < 8; nf++) {
        int f = (wc * 8 + nf) * 16 + lo;
        float bias = b1[f];
#pragma unroll
        for (int r = 0; r < 4; r++) {
            float v = acc[nf][r] + bias;
            float g = 0.5f * v * (1.f + erff(v * 0.70710678f));
            hl[wr * 16 + hi * 4 + r][f] = f2b(g);
        }
    }
    __syncthreads();

    f32x4 acc2[8];
#pragma unroll
    for (int i = 0; i < 8; i++) acc2[i] = (f32x4){0.f, 0.f, 0.f, 0.f};
#pragma unroll
    for (int t = 0; t < 8; t++) {
        short8 bh = ld8(&hl[wr * 16 + lo][t * 32 + hi * 8]);
#pragma unroll
        for (int mf = 0; mf < 8; mf++) {
            short8 a = ld8(w2b + ((wc * 8 + mf) * 16 + lo) * DIM + t * 32 + hi * 8);
            acc2[mf] = mfma16(a, bh, acc2[mf]);
        }
    }
    int bidx = row0 >> 10;
    int n = (rw & 1023) + lo;
#pragma unroll
    for (int mf = 0; mf < 8; mf++) {
#pragma unroll
        for (int r = 0; r < 4; r++) {
            int co = (wc * 8 + mf) * 16 + hi * 4 + r;
            size_t addr = (size_t)bidx * (DIM * NTOK) + (size_t)co * NTOK + n;
            out[addr] = acc2[mf][r] + b2[co] + x[addr];
        }
    }
}

extern "C" void kernel_launch(void* const* d_in, const int* in_sizes, int n_in,
                              void* d_out, int out_size, void* d_ws, size_t ws_size,
                              hipStream_t stream) {
    const float* x      = (const float*)d_in[0];
    const float* proj_w = (const float*)d_in[1];
    const float* proj_b = (const float*)d_in[2];
    const float* w1     = (const float*)d_in[3];
    const float* b1     = (const float*)d_in[4];
    const float* w2     = (const float*)d_in[5];
    const float* b2     = (const float*)d_in[6];
    float* out = (float*)d_out;

    u16* xbf   = (u16*)d_ws;                 // 16*256*1024 = 4,194,304 elems
    u16* nodes = xbf   + 4194304;
    u16* qb    = nodes + 4194304;
    u16* agg   = qb    + 4194304;
    u16* wbf   = agg   + 4194304;            // 3*65536 elems

    pack_kernel <<<1024, 256, 0, stream>>>(x, xbf, nodes);
    wconv_kernel<<<768,  256, 0, stream>>>(proj_w, w1, w2, wbf);
    proj_kernel <<<512,  256, 0, stream>>>(nodes, wbf, proj_b, qb);
    attn_kernel <<<1024, 256, 0, stream>>>(qb, xbf, agg);
    ffn_kernel  <<<256,  512, 0, stream>>>(agg, wbf, b1, b2, x, out);
}

// Round 5
// 116.574 us; speedup vs baseline: 2.1834x; 1.6457x over previous
//
#include <hip/hip_runtime.h>
#include <stdint.h>

typedef unsigned short u16;
typedef __attribute__((ext_vector_type(8))) short short8;
typedef __attribute__((ext_vector_type(4))) float f32x4;

#define NB    16
#define DIM   256
#define NTOK  1024

__device__ __forceinline__ u16 f2b(float f) {
    union { float f; uint32_t u; } v; v.f = f;
    uint32_t u = v.u;
    u += 0x7fffu + ((u >> 16) & 1u);
    return (u16)(u >> 16);
}
__device__ __forceinline__ uint32_t pack2(float a, float b) {
    return (uint32_t)f2b(a) | ((uint32_t)f2b(b) << 16);
}
__device__ __forceinline__ f32x4 mfma16(short8 a, short8 b, f32x4 c) {
    return __builtin_amdgcn_mfma_f32_16x16x32_bf16(a, b, c, 0, 0, 0);
}
__device__ __forceinline__ short8 ld8(const u16* p) {
    return *reinterpret_cast<const short8*>(p);
}
__device__ __forceinline__ void gl_lds(const u16* g, u16* l) {
    __builtin_amdgcn_global_load_lds((const __attribute__((address_space(1))) void*)g,
                                     (__attribute__((address_space(3))) void*)l, 16, 0, 0);
}

// ---------------- Kernel 1: pack x -> xbf (bf16 copy, [C][N]) + nodes (bf16 transpose, [N][C])
__global__ __launch_bounds__(256) void pack_kernel(const float* __restrict__ x,
                                                   u16* __restrict__ xbf,
                                                   u16* __restrict__ nodes) {
    __shared__ float tile[64][65];
    int tid = threadIdx.x;
    int blk = blockIdx.x;          // 1024 blocks
    int b  = blk >> 6;
    int t  = blk & 63;
    int c0 = (t >> 4) << 6;        // 0,64,128,192
    int n0 = (t & 15) << 6;        // 0..960
    const float* xb = x + (size_t)b * (DIM * NTOK);
    u16* xbb = xbf + (size_t)b * (DIM * NTOK);
#pragma unroll
    for (int i = 0; i < 16; i++) {
        int idx = i * 256 + tid;
        int cl = idx >> 6, nl = idx & 63;
        float f = xb[(c0 + cl) * NTOK + n0 + nl];
        tile[cl][nl] = f;
        xbb[(c0 + cl) * NTOK + n0 + nl] = f2b(f);
    }
    __syncthreads();
#pragma unroll
    for (int i = 0; i < 16; i++) {
        int idx = i * 256 + tid;
        int nl = idx >> 6, cl = idx & 63;
        nodes[(size_t)(b * NTOK + n0 + nl) * DIM + c0 + cl] = f2b(tile[cl][nl]);
    }
}

// ---------------- Kernel 2: convert 3 weight matrices to bf16 (proj_w, w1, w2)
__global__ __launch_bounds__(256) void wconv_kernel(const float* __restrict__ a,
                                                    const float* __restrict__ b,
                                                    const float* __restrict__ c,
                                                    u16* __restrict__ o) {
    int i = blockIdx.x * 256 + threadIdx.x;  // 0..196607
    const float* s = (i < 65536) ? a : (i < 131072) ? b : c;
    o[i] = f2b(s[i & 65535]);
}

// ---------------- Kernel 3: q = nodes @ proj_w^T + proj_b  (bf16 out, [N][C])
__global__ __launch_bounds__(256) void proj_kernel(const u16* __restrict__ nodes,
                                                   const u16* __restrict__ wbf,
                                                   const float* __restrict__ pb,
                                                   u16* __restrict__ qb) {
    int lane = threadIdx.x & 63;
    int w = threadIdx.x >> 6;
    int lo = lane & 15, hi = lane >> 4;
    int ch = blockIdx.x & 1;               // column half
    int row0 = (blockIdx.x >> 1) * 64 + w * 16;
    const u16* arow = nodes + (size_t)(row0 + lo) * DIM + hi * 8;
    f32x4 acc[8];
#pragma unroll
    for (int i = 0; i < 8; i++) acc[i] = (f32x4){0.f, 0.f, 0.f, 0.f};
#pragma unroll
    for (int t = 0; t < 8; t++) {
        short8 a = ld8(arow + t * 32);
#pragma unroll
        for (int nf = 0; nf < 8; nf++) {
            short8 bfr = ld8(wbf + ((ch * 8 + nf) * 16 + lo) * DIM + t * 32 + hi * 8);
            acc[nf] = mfma16(a, bfr, acc[nf]);
        }
    }
#pragma unroll
    for (int nf = 0; nf < 8; nf++) {
        int col = (ch * 8 + nf) * 16 + lo;
        float bias = pb[col];
#pragma unroll
        for (int r = 0; r < 4; r++) {
            int row = row0 + hi * 4 + r;
            qb[(size_t)row * DIM + col] = f2b(acc[nf][r] + bias);
        }
    }
}

// ---------------- Kernel 4: flash attention, q-block design with LDS KV staging.
// 256 blocks = 16 q-blocks x 16 batches. Block: 4 waves x 16 q-rows = 64 q.
// KV iterated in 64-row tiles, staged once per block via global_load_lds
// (pre-swizzled source, rule #21), double-buffered. Waves read swizzled
// ds_read_b128 (2-way bank = free). No KV split -> no combine.
__global__ __launch_bounds__(256) void attn_kernel(const u16* __restrict__ qb,
                                                   const u16* __restrict__ xbf,
                                                   u16* __restrict__ agg) {
    __shared__ u16 kls[2][16384];   // [buf][64 kv rows x 256 ch], rows 512B, slot^=(row&7)
    __shared__ u16 vls[2][16384];   // [buf][256 ch x 64 kv],     rows 128B, slot^=(c&7)

    int lane = threadIdx.x & 63;
    int w = threadIdx.x >> 6;            // 0..3
    int lo = lane & 15, hi = lane >> 4;
    int b  = blockIdx.x & 15;            // batch-per-XCD mapping
    int qt = blockIdx.x >> 4;            // 0..15
    int q0 = qt * 64 + w * 16;
    const u16* qbb = qb  + (size_t)b * (NTOK * DIM);
    const u16* xbb = xbf + (size_t)b * (DIM * NTOK);

    // per-lane staging source offsets (element units), loop-invariant
    int kOff[8], vOff[8];
#pragma unroll
    for (int ii = 0; ii < 8; ii++) {
        int i = w * 8 + ii;
        int krow = 2 * i + (lane >> 5);
        int kslot = (lane & 31) ^ (krow & 7);
        kOff[ii] = krow * DIM + kslot * 8;
        int vc = 8 * i + (lane >> 3);
        int vs = (lane & 7) ^ (vc & 7);
        vOff[ii] = vc * NTOK + vs * 8;
    }

    short8 bq[8];
#pragma unroll
    for (int t = 0; t < 8; t++)
        bq[t] = ld8(qbb + (size_t)(q0 + lo) * DIM + t * 32 + hi * 8);

    f32x4 acc[16];
#pragma unroll
    for (int i = 0; i < 16; i++) acc[i] = (f32x4){0.f, 0.f, 0.f, 0.f};
    float m = -1e30f, ell = 0.f;
    const float C1 = 0.0625f * 1.44269504f;
    const float THR = 11.5f;

    // prologue: stage tile 0 into buf 0
#pragma unroll
    for (int ii = 0; ii < 8; ii++) {
        gl_lds(qbb + kOff[ii],        &kls[0][(w * 8 + ii) * 512]);
        gl_lds(xbb + vOff[ii],        &vls[0][(w * 8 + ii) * 512]);
    }
    __syncthreads();

    for (int tt = 0; tt < 16; tt++) {
        int buf = tt & 1;
        if (tt < 15) {
            int kvE = (tt + 1) * 64;     // next tile kv base (rows)
#pragma unroll
            for (int ii = 0; ii < 8; ii++) {
                gl_lds(qbb + kvE * DIM + kOff[ii], &kls[buf ^ 1][(w * 8 + ii) * 512]);
                gl_lds(xbb + kvE       + vOff[ii], &vls[buf ^ 1][(w * 8 + ii) * 512]);
            }
        }
        const u16* kb = &kls[buf][0];
        const u16* vb = &vls[buf][0];

        // QK^T: 4 score frags, kv = 64 rows
        f32x4 sfr[4];
#pragma unroll
        for (int s = 0; s < 4; s++) sfr[s] = (f32x4){0.f, 0.f, 0.f, 0.f};
#pragma unroll
        for (int t = 0; t < 8; t++) {
            int sl = ((t * 4 + hi) ^ (lo & 7)) * 8;
#pragma unroll
            for (int s = 0; s < 4; s++) {
                short8 a = ld8(kb + (s * 16 + lo) * DIM + sl);
                sfr[s] = mfma16(a, bq[t], sfr[s]);
            }
        }

        float p[16];
        float pm = -1e30f;
#pragma unroll
        for (int s = 0; s < 4; s++)
#pragma unroll
            for (int r = 0; r < 4; r++) {
                p[s * 4 + r] = sfr[s][r] * C1;
                pm = fmaxf(pm, p[s * 4 + r]);
            }
        pm = fmaxf(pm, __shfl_xor(pm, 16));
        pm = fmaxf(pm, __shfl_xor(pm, 32));
        if (!__all(pm <= m + THR)) {
            float mnew = fmaxf(m, pm);
            float sc = exp2f(m - mnew);
            ell *= sc;
#pragma unroll
            for (int i = 0; i < 16; i++) {
                acc[i][0] *= sc; acc[i][1] *= sc; acc[i][2] *= sc; acc[i][3] *= sc;
            }
            m = mnew;
        }
        float psum = 0.f;
#pragma unroll
        for (int i = 0; i < 16; i++) {
            p[i] = exp2f(p[i] - m);
            psum += p[i];
        }
        psum += __shfl_xor(psum, 16);
        psum += __shfl_xor(psum, 32);
        ell += psum;

        // redistribute P into B-frag layout, one frag per 32-kv half
        short8 pfrag[2];
#pragma unroll
        for (int h = 0; h < 2; h++) {
            uint32_t pl0 = pack2(p[h * 8 + 0], p[h * 8 + 1]);
            uint32_t ph0 = pack2(p[h * 8 + 2], p[h * 8 + 3]);
            uint32_t pl1 = pack2(p[h * 8 + 4], p[h * 8 + 5]);
            uint32_t ph1 = pack2(p[h * 8 + 6], p[h * 8 + 7]);
            int srcA = ((hi & 1) << 5) | lo;
            int srcB = srcA + 16;
            uint32_t w0a = __shfl(pl0, srcA), w0b = __shfl(pl1, srcA);
            uint32_t w1a = __shfl(ph0, srcA), w1b = __shfl(ph1, srcA);
            uint32_t w2a = __shfl(pl0, srcB), w2b = __shfl(pl1, srcB);
            uint32_t w3a = __shfl(ph0, srcB), w3b = __shfl(ph1, srcB);
            bool sel = (hi >= 2);
            union { uint32_t u[4]; short8 v; } pu;
            pu.u[0] = sel ? w0b : w0a;
            pu.u[1] = sel ? w1b : w1a;
            pu.u[2] = sel ? w2b : w2a;
            pu.u[3] = sel ? w3b : w3a;
            pfrag[h] = pu.v;
        }

        // PV: acc[mf] += V^T-frag x P-frag, two 32-kv k-steps
#pragma unroll
        for (int h = 0; h < 2; h++) {
            int sl = ((h * 4 + hi) ^ (lo & 7)) * 8;
#pragma unroll
            for (int mf = 0; mf < 16; mf++) {
                short8 a = ld8(vb + (mf * 16 + lo) * 64 + sl);
                acc[mf] = mfma16(a, pfrag[h], acc[mf]);
            }
        }
        __syncthreads();
    }

    float rinv = 1.f / ell;
#pragma unroll
    for (int mf = 0; mf < 16; mf++) {
        ushort4 st;
        st.x = f2b(acc[mf][0] * rinv);
        st.y = f2b(acc[mf][1] * rinv);
        st.z = f2b(acc[mf][2] * rinv);
        st.w = f2b(acc[mf][3] * rinv);
        *reinterpret_cast<ushort4*>(agg + (size_t)(b * NTOK + q0 + lo) * DIM + mf * 16 + hi * 4) = st;
    }
}

// ---------------- Kernel 5: FFN + residual, 8-wave blocks (4 rowtiles x 2 colhalves).
__global__ __launch_bounds__(512) void ffn_kernel(const u16* __restrict__ agg,
                                                  const u16* __restrict__ wbf,
                                                  const float* __restrict__ b1,
                                                  const float* __restrict__ b2,
                                                  const float* __restrict__ x,
                                                  float* __restrict__ out) {
    __shared__ u16 hl[64][264];
    int lane = threadIdx.x & 63;
    int w = threadIdx.x >> 6;        // 0..7
    int wr = w & 3, wc = w >> 2;
    int lo = lane & 15, hi = lane >> 4;
    int row0 = blockIdx.x * 64;      // 256 blocks
    int rw = row0 + wr * 16;
    const u16* w1b = wbf + 65536;
    const u16* w2b = wbf + 131072;

    f32x4 acc[8];
#pragma unroll
    for (int i = 0; i < 8; i++) acc[i] = (f32x4){0.f, 0.f, 0.f, 0.f};
    const u16* arow = agg + (size_t)(rw + lo) * DIM + hi * 8;
#pragma unroll
    for (int t = 0; t < 8; t++) {
        short8 a = ld8(arow + t * 32);
#pragma unroll
        for (int nf = 0; nf < 8; nf++) {
            short8 bfr = ld8(w1b + ((wc * 8 + nf) * 16 + lo) * DIM + t * 32 + hi * 8);
            acc[nf] = mfma16(a, bfr, acc[nf]);
        }
    }
#pragma unroll
    for (int nf = 0; nf < 8; nf++) {
        int f = (wc * 8 + nf) * 16 + lo;
        float bias = b1[f];
#pragma unroll
        for (int r = 0; r < 4; r++) {
            float v = acc[nf][r] + bias;
            float g = 0.5f * v * (1.f + erff(v * 0.70710678f));
            hl[wr * 16 + hi * 4 + r][f] = f2b(g);
        }
    }
    __syncthreads();

    f32x4 acc2[8];
#pragma unroll
    for (int i = 0; i < 8; i++) acc2[i] = (f32x4){0.f, 0.f, 0.f, 0.f};
#pragma unroll
    for (int t = 0; t < 8; t++) {
        short8 bh = ld8(&hl[wr * 16 + lo][t * 32 + hi * 8]);
#pragma unroll
        for (int mf = 0; mf < 8; mf++) {
            short8 a = ld8(w2b + ((wc * 8 + mf) * 16 + lo) * DIM + t * 32 + hi * 8);
            acc2[mf] = mfma16(a, bh, acc2[mf]);
        }
    }
    int bidx = row0 >> 10;
    int n = (rw & 1023) + lo;
#pragma unroll
    for (int mf = 0; mf < 8; mf++) {
#pragma unroll
        for (int r = 0; r < 4; r++) {
            int co = (wc * 8 + mf) * 16 + hi * 4 + r;
            size_t addr = (size_t)bidx * (DIM * NTOK) + (size_t)co * NTOK + n;
            out[addr] = acc2[mf][r] + b2[co] + x[addr];
        }
    }
}

extern "C" void kernel_launch(void* const* d_in, const int* in_sizes, int n_in,
                              void* d_out, int out_size, void* d_ws, size_t ws_size,
                              hipStream_t stream) {
    const float* x      = (const float*)d_in[0];
    const float* proj_w = (const float*)d_in[1];
    const float* proj_b = (const float*)d_in[2];
    const float* w1     = (const float*)d_in[3];
    const float* b1     = (const float*)d_in[4];
    const float* w2     = (const float*)d_in[5];
    const float* b2     = (const float*)d_in[6];
    float* out = (float*)d_out;

    u16* xbf   = (u16*)d_ws;                 // 16*256*1024 = 4,194,304 elems
    u16* nodes = xbf   + 4194304;
    u16* qb    = nodes + 4194304;
    u16* agg   = qb    + 4194304;
    u16* wbf   = agg   + 4194304;            // 3*65536 elems

    pack_kernel <<<1024, 256, 0, stream>>>(x, xbf, nodes);
    wconv_kernel<<<768,  256, 0, stream>>>(proj_w, w1, w2, wbf);
    proj_kernel <<<512,  256, 0, stream>>>(nodes, wbf, proj_b, qb);
    attn_kernel <<<256,  256, 0, stream>>>(qb, xbf, agg);
    ffn_kernel  <<<256,  512, 0, stream>>>(agg, wbf, b1, b2, x, out);
}